// Round 1
// baseline (3838.714 us; speedup 1.0000x reference)
//
#include <hip/hip_runtime.h>
#include <hip/hip_fp16.h>
#include <cstdint>

#define BATCH 256
#define SEQ   2048
#define IN_DIM 4
#define HID   256
#define G4    1024   // 4*HID

// ---------- helpers ----------

typedef _Float16 h2_t __attribute__((ext_vector_type(2)));

union U32H2 { uint32_t u; h2_t h; __half2 hh; };

__device__ __forceinline__ float fdot2(uint32_t w, uint32_t h, float acc) {
#if __has_builtin(__builtin_amdgcn_fdot2)
    U32H2 a; a.u = w; U32H2 b; b.u = h;
    return __builtin_amdgcn_fdot2(a.h, b.h, acc, false);
#else
    U32H2 a; a.u = w; U32H2 b; b.u = h;
    float2 fa = __half22float2(a.hh), fb = __half22float2(b.hh);
    return acc + fa.x * fb.x + fa.y * fb.y;
#endif
}

__device__ __forceinline__ uint32_t pack_h2(float a, float b) {
    U32H2 u; u.hh = __floats2half2_rn(a, b); return u.u;
}

__device__ __forceinline__ float sigmoidf_(float x) {
    return 1.0f / (1.0f + __expf(-x));
}
__device__ __forceinline__ float tanhf_(float x) {
    // tanh(x) = 1 - 2/(exp(2x)+1); saturates correctly at +/-inf
    return 1.0f - 2.0f / (__expf(2.0f * x) + 1.0f);
}

// ---------- ws layout (bytes) ----------
// wreg  fp16 pairs [96][1024] : 393216
// wtail fp16 pairs [16][1024][2dw] : 131072   @ 393216
// bias  fp32 [1024]                : 4096     @ 524288
// convf fp32 [256]                 : 1024     @ 528384
// ksim  fp32 [256]                 : 1024     @ 529408
// h_out fp32 [256][256]            : 262144   @ 530432
#define OFF_WTAIL 393216
#define OFF_BIAS  524288
#define OFF_CONVF 528384
#define OFF_KSIM  529408
#define OFF_HOUT  530432

// ---------- prep: fp16 conversion + bias fuse ----------
__global__ void prep_kernel(const float* __restrict__ Whh,
                            const float* __restrict__ bih,
                            const float* __restrict__ bhh,
                            uint32_t* __restrict__ wreg,
                            uint32_t* __restrict__ wtail,
                            float* __restrict__ bias) {
    int gid = blockIdx.x * blockDim.x + threadIdx.x;  // 0..131071
    int row = gid >> 7;      // 0..1023
    int pr  = gid & 127;     // pair index, cols 2pr, 2pr+1
    float a = Whh[row * HID + 2 * pr];
    float b = Whh[row * HID + 2 * pr + 1];
    uint32_t p = pack_h2(a, b);
    if (pr < 96) {
        wreg[pr * G4 + row] = p;
    } else {
        int q = pr - 96;            // 0..31
        int c = q >> 1, d = q & 1;  // chunk 0..15, dword 0..1
        wtail[(c * G4 + row) * 2 + d] = p;
    }
    if (gid < G4) bias[gid] = bih[gid] + bhh[gid];
}

// ---------- features: conv mean + RBF kernel sim ----------
__global__ void feat_kernel(const float* __restrict__ x,
                            const float* __restrict__ conv_w,
                            const float* __restrict__ conv_b,
                            float* __restrict__ convf,
                            float* __restrict__ ksim) {
    int b = blockIdx.x, t = threadIdx.x;  // 256 threads
    const float4* xb = (const float4*)(x + (size_t)b * SEQ * IN_DIM);
    float cw0 = conv_w[0], cw1 = conv_w[1], cw2 = conv_w[2], cw3 = conv_w[3];
    float cb = conv_b[0];
    float s_sig = 0.f, s_sq = 0.f;
#pragma unroll
    for (int k = 0; k < 8; ++k) {
        int s = t + k * 256;
        float4 v = xb[s];
        float d = v.x * cw0 + v.y * cw1 + v.z * cw2 + v.w * cw3 + cb;
        s_sig += sigmoidf_(d);
        s_sq  += v.x * v.x + v.y * v.y + v.z * v.z + v.w * v.w;
    }
    __shared__ float sA[256], sB[256];
    sA[t] = s_sig; sB[t] = s_sq;
    __syncthreads();
    for (int off = 128; off > 0; off >>= 1) {
        if (t < off) { sA[t] += sA[t + off]; sB[t] += sB[t + off]; }
        __syncthreads();
    }
    if (t == 0) {
        convf[b] = sA[0] * (1.0f / 2048.0f);
        ksim[b]  = __expf(-sB[0]);
    }
}

// ---------- LSTM recurrence: 1 sample per block ----------
// 512 threads: thread t owns gate rows r1=t and r2=t+512.
//  t<256  : rows = (i_u, g_u), u=t      -> computes p=sigmoid(i)*tanh(g)
//  t>=256 : rows = (f_u, o_u), u=t-256  -> owns c_u, computes h_u
// LDS: wtail copy [16][1024][2dw] (128KB) + h double-buffer fp16 (2x512B) + p[256] f32
#define TAIL_DW (16 * 1024 * 2)

__global__ __launch_bounds__(512, 2)
void recur_kernel(const float* __restrict__ x,
                  const float* __restrict__ Wih,
                  const uint32_t* __restrict__ wreg,
                  const uint32_t* __restrict__ wtail,
                  const float* __restrict__ bias,
                  float* __restrict__ h_out) {
    extern __shared__ uint32_t smem[];
    uint32_t* tail  = smem;                 // TAIL_DW dwords
    uint32_t* hbuf0 = smem + TAIL_DW;       // 128 dwords (256 fp16)
    uint32_t* hbuf1 = hbuf0 + 128;          // 128 dwords
    float*    pbuf  = (float*)(hbuf1 + 128);// 256 floats

    const int b = blockIdx.x;
    const int t = threadIdx.x;
    const int r1 = t, r2 = t + 512;

    // stage w-tail into LDS (coalesced, layout identical)
    {
        const uint4* src = (const uint4*)wtail;
        uint4* dst = (uint4*)tail;
#pragma unroll
        for (int i = 0; i < 16; ++i) dst[t + i * 512] = src[t + i * 512];
    }
    if (t < 128) hbuf0[t] = 0u;  // h = 0 (fp16 zeros)

    // register-resident weights: cols 0..191 of rows r1, r2
    uint32_t w1[96], w2[96];
#pragma unroll
    for (int k = 0; k < 96; ++k) {
        w1[k] = wreg[k * G4 + r1];
        w2[k] = wreg[k * G4 + r2];
    }
    const float4 wih1 = ((const float4*)Wih)[r1];
    const float4 wih2 = ((const float4*)Wih)[r2];
    const float bias1 = bias[r1], bias2 = bias[r2];

    float c_state = 0.f;
    float h_last = 0.f;
    const float4* xb = (const float4*)(x + (size_t)b * SEQ * IN_DIM);

    __syncthreads();

    uint32_t* hr = hbuf0;
    uint32_t* hw = hbuf1;

    for (int s = 0; s < SEQ; ++s) {
        float4 xt = xb[s];
        float a1  = bias1 + xt.x * wih1.x + xt.y * wih1.y + xt.z * wih1.z + xt.w * wih1.w;
        float a2  = bias2 + xt.x * wih2.x + xt.y * wih2.y + xt.z * wih2.z + xt.w * wih2.w;
        float a1b = 0.f, a2b = 0.f;

        // main part: cols 0..191 from registers, h broadcast from LDS
#pragma unroll
        for (int c = 0; c < 6; ++c) {
            const uint4 q0 = ((const uint4*)hr)[c * 4 + 0];
            const uint4 q1 = ((const uint4*)hr)[c * 4 + 1];
            const uint4 q2 = ((const uint4*)hr)[c * 4 + 2];
            const uint4 q3 = ((const uint4*)hr)[c * 4 + 3];
            const uint32_t hh[16] = {q0.x, q0.y, q0.z, q0.w,
                                     q1.x, q1.y, q1.z, q1.w,
                                     q2.x, q2.y, q2.z, q2.w,
                                     q3.x, q3.y, q3.z, q3.w};
#pragma unroll
            for (int i = 0; i < 16; ++i) {
                const int p = c * 16 + i;
                if (i & 1) {
                    a1b = fdot2(w1[p], hh[i], a1b);
                    a2b = fdot2(w2[p], hh[i], a2b);
                } else {
                    a1 = fdot2(w1[p], hh[i], a1);
                    a2 = fdot2(w2[p], hh[i], a2);
                }
            }
        }
        // tail: cols 192..255 from LDS
#pragma unroll 4
        for (int c = 0; c < 16; ++c) {
            const uint2 wt1 = ((const uint2*)tail)[c * G4 + r1];
            const uint2 wt2 = ((const uint2*)tail)[c * G4 + r2];
            const uint2 hh  = ((const uint2*)hr)[48 + c];
            a1  = fdot2(wt1.x, hh.x, a1);
            a1b = fdot2(wt1.y, hh.y, a1b);
            a2  = fdot2(wt2.x, hh.x, a2);
            a2b = fdot2(wt2.y, hh.y, a2b);
        }
        const float z1 = a1 + a1b;
        const float z2 = a2 + a2b;

        if (t < 256) {
            // i, g -> p = sigmoid(i)*tanh(g)
            pbuf[t] = sigmoidf_(z1) * tanhf_(z2);
        }
        const float fg = sigmoidf_(z1);  // f (valid for t>=256)
        const float og = sigmoidf_(z2);  // o
        __syncthreads();
        if (t >= 256) {
            const int u = t - 256;
            c_state = fg * c_state + pbuf[u];
            h_last = og * tanhf_(c_state);
            ((__half*)hw)[u] = __float2half_rn(h_last);
        }
        __syncthreads();
        uint32_t* tmp = hr; hr = hw; hw = tmp;
    }

    if (t >= 256) h_out[b * HID + (t - 256)] = h_last;
}

// ---------- head: fc + relu + out + softmax ----------
__global__ void head_kernel(const float* __restrict__ fc_w,
                            const float* __restrict__ fc_b,
                            const float* __restrict__ out_w,
                            const float* __restrict__ out_b,
                            const float* __restrict__ convf,
                            const float* __restrict__ ksim,
                            const float* __restrict__ h_out,
                            float* __restrict__ out) {
    int b = blockIdx.x, j = threadIdx.x;  // 256 threads
    const float* hrow = h_out + b * HID;
    const float* w = fc_w + j * (HID + 2);
    float acc = fc_b[j] + w[0] * convf[b] + w[HID + 1] * ksim[b];
#pragma unroll 8
    for (int k = 0; k < HID; ++k) acc += w[1 + k] * hrow[k];
    float hid = fmaxf(acc, 0.f);
    __shared__ float r0[256], r1[256];
    r0[j] = hid * out_w[j];
    r1[j] = hid * out_w[HID + j];
    __syncthreads();
    for (int off = 128; off > 0; off >>= 1) {
        if (j < off) { r0[j] += r0[j + off]; r1[j] += r1[j + off]; }
        __syncthreads();
    }
    if (j == 0) {
        float l0 = r0[0] + out_b[0];
        float l1 = r1[0] + out_b[1];
        float m = fmaxf(l0, l1);
        float e0 = __expf(l0 - m), e1 = __expf(l1 - m);
        float inv = 1.0f / (e0 + e1);
        out[b * 2 + 0] = e0 * inv;
        out[b * 2 + 1] = e1 * inv;
    }
}

// ---------- launch ----------
extern "C" void kernel_launch(void* const* d_in, const int* in_sizes, int n_in,
                              void* d_out, int out_size, void* d_ws, size_t ws_size,
                              hipStream_t stream) {
    const float* x      = (const float*)d_in[0];
    const float* conv_w = (const float*)d_in[1];
    const float* conv_b = (const float*)d_in[2];
    const float* Wih    = (const float*)d_in[3];
    const float* Whh    = (const float*)d_in[4];
    const float* bih    = (const float*)d_in[5];
    const float* bhh    = (const float*)d_in[6];
    const float* fcw    = (const float*)d_in[7];
    const float* fcb    = (const float*)d_in[8];
    const float* outw   = (const float*)d_in[9];
    const float* outb   = (const float*)d_in[10];
    float* out = (float*)d_out;

    uint8_t* ws = (uint8_t*)d_ws;
    uint32_t* wreg  = (uint32_t*)ws;
    uint32_t* wtail = (uint32_t*)(ws + OFF_WTAIL);
    float* bias  = (float*)(ws + OFF_BIAS);
    float* convf = (float*)(ws + OFF_CONVF);
    float* ksim  = (float*)(ws + OFF_KSIM);
    float* h_out = (float*)(ws + OFF_HOUT);

    prep_kernel<<<512, 256, 0, stream>>>(Whh, bih, bhh, wreg, wtail, bias);
    feat_kernel<<<BATCH, 256, 0, stream>>>(x, conv_w, conv_b, convf, ksim);

    const size_t smem_bytes = (size_t)(TAIL_DW + 128 + 128 + 256) * 4;  // 133120 B
    hipFuncSetAttribute((const void*)recur_kernel,
                        hipFuncAttributeMaxDynamicSharedMemorySize, (int)smem_bytes);
    recur_kernel<<<BATCH, 512, smem_bytes, stream>>>(x, Wih, wreg, wtail, bias, h_out);

    head_kernel<<<BATCH, 256, 0, stream>>>(fcw, fcb, outw, outb, convf, ksim, h_out, out);
}

// Round 2
// 3243.835 us; speedup vs baseline: 1.1834x; 1.1834x over previous
//
#include <hip/hip_runtime.h>
#include <hip/hip_fp16.h>
#include <cstdint>

#define BATCH 256
#define SEQ   2048
#define IN_DIM 4
#define HID   256
#define G4    1024   // 4*HID

// ---------- helpers ----------

typedef _Float16 h2_t __attribute__((ext_vector_type(2)));

union U32H2 { uint32_t u; h2_t h; __half2 hh; };

__device__ __forceinline__ float fdot2(uint32_t w, uint32_t h, float acc) {
#if __has_builtin(__builtin_amdgcn_fdot2)
    U32H2 a; a.u = w; U32H2 b; b.u = h;
    return __builtin_amdgcn_fdot2(a.h, b.h, acc, false);
#else
    U32H2 a; a.u = w; U32H2 b; b.u = h;
    float2 fa = __half22float2(a.hh), fb = __half22float2(b.hh);
    return acc + fa.x * fb.x + fa.y * fb.y;
#endif
}

__device__ __forceinline__ uint32_t pack_h2(float a, float b) {
    U32H2 u; u.hh = __floats2half2_rn(a, b); return u.u;
}

__device__ __forceinline__ float sigmoidf_(float x) {
    return 1.0f / (1.0f + __expf(-x));
}
__device__ __forceinline__ float tanhf_(float x) {
    return 1.0f - 2.0f / (__expf(2.0f * x) + 1.0f);
}

// ---------- ws layout (bytes) ----------
// wreg  fp16 pairs [96][1024]        : 393216
// wtail fp16 pairs [8][1024][uint4]  : 131072   @ 393216
// bias  fp32 [1024]                  : 4096     @ 524288
// convf fp32 [256]                   : 1024     @ 528384
// ksim  fp32 [256]                   : 1024     @ 529408
// h_out fp32 [256][256]              : 262144   @ 530432
#define OFF_WTAIL 393216
#define OFF_BIAS  524288
#define OFF_CONVF 528384
#define OFF_KSIM  529408
#define OFF_HOUT  530432

// ---------- prep: fp16 conversion + bias fuse ----------
__global__ void prep_kernel(const float* __restrict__ Whh,
                            const float* __restrict__ bih,
                            const float* __restrict__ bhh,
                            uint32_t* __restrict__ wreg,
                            uint32_t* __restrict__ wtail,
                            float* __restrict__ bias) {
    int gid = blockIdx.x * blockDim.x + threadIdx.x;  // 0..131071
    int row = gid >> 7;      // 0..1023
    int pr  = gid & 127;     // pair index, cols 2pr, 2pr+1
    float a = Whh[row * HID + 2 * pr];
    float b = Whh[row * HID + 2 * pr + 1];
    uint32_t p = pack_h2(a, b);
    if (pr < 96) {
        wreg[pr * G4 + row] = p;
    } else {
        int q = pr - 96;            // 0..31
        int c = q >> 2, d = q & 3;  // uint4 chunk 0..7, dword 0..3
        wtail[(c * G4 + row) * 4 + d] = p;
    }
    if (gid < G4) bias[gid] = bih[gid] + bhh[gid];
}

// ---------- features: conv mean + RBF kernel sim ----------
__global__ void feat_kernel(const float* __restrict__ x,
                            const float* __restrict__ conv_w,
                            const float* __restrict__ conv_b,
                            float* __restrict__ convf,
                            float* __restrict__ ksim) {
    int b = blockIdx.x, t = threadIdx.x;  // 256 threads
    const float4* xb = (const float4*)(x + (size_t)b * SEQ * IN_DIM);
    float cw0 = conv_w[0], cw1 = conv_w[1], cw2 = conv_w[2], cw3 = conv_w[3];
    float cb = conv_b[0];
    float s_sig = 0.f, s_sq = 0.f;
#pragma unroll
    for (int k = 0; k < 8; ++k) {
        int s = t + k * 256;
        float4 v = xb[s];
        float d = v.x * cw0 + v.y * cw1 + v.z * cw2 + v.w * cw3 + cb;
        s_sig += sigmoidf_(d);
        s_sq  += v.x * v.x + v.y * v.y + v.z * v.z + v.w * v.w;
    }
    __shared__ float sA[256], sB[256];
    sA[t] = s_sig; sB[t] = s_sq;
    __syncthreads();
    for (int off = 128; off > 0; off >>= 1) {
        if (t < off) { sA[t] += sA[t + off]; sB[t] += sB[t + off]; }
        __syncthreads();
    }
    if (t == 0) {
        convf[b] = sA[0] * (1.0f / 2048.0f);
        ksim[b]  = __expf(-sB[0]);
    }
}

// ---------- LSTM recurrence: 1 sample per block ----------
// 512 threads: thread t owns gate rows r1=t and r2=t+512.
//  t<256  : rows = (i_u, g_u), u=t      -> computes p=sigmoid(i)*tanh(g)
//  t>=256 : rows = (f_u, o_u), u=t-256  -> owns c_u, computes h_u
// LDS: wtail copy [8][1024] uint4 (128KB) + h double-buffer fp16 (2x512B) + p[256] f32
//
// amdgpu_waves_per_eu(2,2): LDS caps us at 1 block/CU = 8 waves = 2/EU anyway;
// clamping max waves tells the register allocator it may use the full 256-VGPR
// budget, so w1[96]/w2[96] stay truly register-resident (round-1 showed the
// compiler sinking the weight loads into the loop at VGPR_Count=120).
#define TAIL_DW (8 * 1024 * 4)

__global__ __launch_bounds__(512)
__attribute__((amdgpu_waves_per_eu(2, 2)))
void recur_kernel(const float* __restrict__ x,
                  const float* __restrict__ Wih,
                  const uint32_t* __restrict__ wreg,
                  const uint32_t* __restrict__ wtail,
                  const float* __restrict__ bias,
                  float* __restrict__ h_out) {
    extern __shared__ uint32_t smem[];
    uint32_t* tail  = smem;                 // TAIL_DW dwords (8192 uint4)
    uint32_t* hbuf0 = smem + TAIL_DW;       // 128 dwords (256 fp16)
    uint32_t* hbuf1 = hbuf0 + 128;          // 128 dwords
    float*    pbuf  = (float*)(hbuf1 + 128);// 256 floats

    const int b = blockIdx.x;
    const int t = threadIdx.x;
    const int r1 = t, r2 = t + 512;

    // stage w-tail into LDS (coalesced, layout identical)
    {
        const uint4* src = (const uint4*)wtail;
        uint4* dst = (uint4*)tail;
#pragma unroll
        for (int i = 0; i < 16; ++i) dst[t + i * 512] = src[t + i * 512];
    }
    if (t < 128) hbuf0[t] = 0u;  // h = 0 (fp16 zeros)

    // register-resident weights: pair-cols 0..95 of rows r1, r2
    uint32_t w1[96], w2[96];
#pragma unroll
    for (int k = 0; k < 96; ++k) {
        w1[k] = wreg[k * G4 + r1];
        w2[k] = wreg[k * G4 + r2];
    }
    // opaque no-op: pin values in VGPRs, forbid rematerialized reloads
#pragma unroll
    for (int k = 0; k < 96; ++k) {
        asm volatile("" : "+v"(w1[k]), "+v"(w2[k]));
    }

    const float4 wih1 = ((const float4*)Wih)[r1];
    const float4 wih2 = ((const float4*)Wih)[r2];
    const float bias1 = bias[r1], bias2 = bias[r2];

    float c_state = 0.f;
    float h_last = 0.f;
    const float4* xb = (const float4*)(x + (size_t)b * SEQ * IN_DIM);

    const uint4* tail4_1 = (const uint4*)tail + r1;   // + c*G4 per chunk
    const uint4* tail4_2 = (const uint4*)tail + r2;

    __syncthreads();

    uint32_t* hr = hbuf0;
    uint32_t* hw = hbuf1;

    for (int s = 0; s < SEQ; ++s) {
        const float4 xt = xb[s];
        float a1  = bias1 + xt.x * wih1.x + xt.y * wih1.y + xt.z * wih1.z + xt.w * wih1.w;
        float a2  = bias2 + xt.x * wih2.x + xt.y * wih2.y + xt.z * wih2.z + xt.w * wih2.w;
        float a1b = 0.f, a2b = 0.f;

        const uint4* hr4 = (const uint4*)hr;

        // main part: pair-cols 0..95 from registers, h broadcast from LDS
#pragma unroll
        for (int c = 0; c < 24; ++c) {
            const uint4 h4 = hr4[c];
            a1  = fdot2(w1[4 * c + 0], h4.x, a1);
            a2  = fdot2(w2[4 * c + 0], h4.x, a2);
            a1b = fdot2(w1[4 * c + 1], h4.y, a1b);
            a2b = fdot2(w2[4 * c + 1], h4.y, a2b);
            a1  = fdot2(w1[4 * c + 2], h4.z, a1);
            a2  = fdot2(w2[4 * c + 2], h4.z, a2);
            a1b = fdot2(w1[4 * c + 3], h4.w, a1b);
            a2b = fdot2(w2[4 * c + 3], h4.w, a2b);
        }
        // tail: pair-cols 96..127 from LDS (b128 reads)
#pragma unroll
        for (int c = 0; c < 8; ++c) {
            const uint4 wt1 = tail4_1[c * G4];
            const uint4 wt2 = tail4_2[c * G4];
            const uint4 h4  = hr4[24 + c];
            a1  = fdot2(wt1.x, h4.x, a1);
            a2  = fdot2(wt2.x, h4.x, a2);
            a1b = fdot2(wt1.y, h4.y, a1b);
            a2b = fdot2(wt2.y, h4.y, a2b);
            a1  = fdot2(wt1.z, h4.z, a1);
            a2  = fdot2(wt2.z, h4.z, a2);
            a1b = fdot2(wt1.w, h4.w, a1b);
            a2b = fdot2(wt2.w, h4.w, a2b);
        }
        const float z1 = a1 + a1b;
        const float z2 = a2 + a2b;

        if (t < 256) {
            // i, g -> p = sigmoid(i)*tanh(g)
            pbuf[t] = sigmoidf_(z1) * tanhf_(z2);
        }
        const float fg = sigmoidf_(z1);  // f (valid for t>=256)
        const float og = sigmoidf_(z2);  // o
        __syncthreads();
        if (t >= 256) {
            const int u = t - 256;
            c_state = fg * c_state + pbuf[u];
            h_last = og * tanhf_(c_state);
            ((__half*)hw)[u] = __float2half_rn(h_last);
        }
        __syncthreads();
        uint32_t* tmp = hr; hr = hw; hw = tmp;
    }

    if (t >= 256) h_out[b * HID + (t - 256)] = h_last;
}

// ---------- head: fc + relu + out + softmax ----------
__global__ void head_kernel(const float* __restrict__ fc_w,
                            const float* __restrict__ fc_b,
                            const float* __restrict__ out_w,
                            const float* __restrict__ out_b,
                            const float* __restrict__ convf,
                            const float* __restrict__ ksim,
                            const float* __restrict__ h_out,
                            float* __restrict__ out) {
    int b = blockIdx.x, j = threadIdx.x;  // 256 threads
    const float* hrow = h_out + b * HID;
    const float* w = fc_w + j * (HID + 2);
    float acc = fc_b[j] + w[0] * convf[b] + w[HID + 1] * ksim[b];
#pragma unroll 8
    for (int k = 0; k < HID; ++k) acc += w[1 + k] * hrow[k];
    float hid = fmaxf(acc, 0.f);
    __shared__ float r0[256], r1[256];
    r0[j] = hid * out_w[j];
    r1[j] = hid * out_w[HID + j];
    __syncthreads();
    for (int off = 128; off > 0; off >>= 1) {
        if (j < off) { r0[j] += r0[j + off]; r1[j] += r1[j + off]; }
        __syncthreads();
    }
    if (j == 0) {
        float l0 = r0[0] + out_b[0];
        float l1 = r1[0] + out_b[1];
        float m = fmaxf(l0, l1);
        float e0 = __expf(l0 - m), e1 = __expf(l1 - m);
        float inv = 1.0f / (e0 + e1);
        out[b * 2 + 0] = e0 * inv;
        out[b * 2 + 1] = e1 * inv;
    }
}

// ---------- launch ----------
extern "C" void kernel_launch(void* const* d_in, const int* in_sizes, int n_in,
                              void* d_out, int out_size, void* d_ws, size_t ws_size,
                              hipStream_t stream) {
    const float* x      = (const float*)d_in[0];
    const float* conv_w = (const float*)d_in[1];
    const float* conv_b = (const float*)d_in[2];
    const float* Wih    = (const float*)d_in[3];
    const float* Whh    = (const float*)d_in[4];
    const float* bih    = (const float*)d_in[5];
    const float* bhh    = (const float*)d_in[6];
    const float* fcw    = (const float*)d_in[7];
    const float* fcb    = (const float*)d_in[8];
    const float* outw   = (const float*)d_in[9];
    const float* outb   = (const float*)d_in[10];
    float* out = (float*)d_out;

    uint8_t* ws = (uint8_t*)d_ws;
    uint32_t* wreg  = (uint32_t*)ws;
    uint32_t* wtail = (uint32_t*)(ws + OFF_WTAIL);
    float* bias  = (float*)(ws + OFF_BIAS);
    float* convf = (float*)(ws + OFF_CONVF);
    float* ksim  = (float*)(ws + OFF_KSIM);
    float* h_out = (float*)(ws + OFF_HOUT);

    prep_kernel<<<512, 256, 0, stream>>>(Whh, bih, bhh, wreg, wtail, bias);
    feat_kernel<<<BATCH, 256, 0, stream>>>(x, conv_w, conv_b, convf, ksim);

    const size_t smem_bytes = (size_t)(TAIL_DW + 128 + 128 + 256) * 4;  // 133120 B
    hipFuncSetAttribute((const void*)recur_kernel,
                        hipFuncAttributeMaxDynamicSharedMemorySize, (int)smem_bytes);
    recur_kernel<<<BATCH, 512, smem_bytes, stream>>>(x, Wih, wreg, wtail, bias, h_out);

    head_kernel<<<BATCH, 256, 0, stream>>>(fcw, fcb, outw, outb, convf, ksim, h_out, out);
}

// Round 3
// 3222.737 us; speedup vs baseline: 1.1911x; 1.0065x over previous
//
#include <hip/hip_runtime.h>
#include <hip/hip_fp16.h>
#include <cstdint>

#define BATCH 256
#define SEQ   2048
#define IN_DIM 4
#define HID   256
#define G4    1024   // 4*HID

// ---------- helpers ----------

typedef _Float16 h2_t __attribute__((ext_vector_type(2)));

union U32H2 { uint32_t u; h2_t h; __half2 hh; };

__device__ __forceinline__ float fdot2(uint32_t w, uint32_t h, float acc) {
#if __has_builtin(__builtin_amdgcn_fdot2)
    U32H2 a; a.u = w; U32H2 b; b.u = h;
    return __builtin_amdgcn_fdot2(a.h, b.h, acc, false);
#else
    U32H2 a; a.u = w; U32H2 b; b.u = h;
    float2 fa = __half22float2(a.hh), fb = __half22float2(b.hh);
    return acc + fa.x * fb.x + fa.y * fb.y;
#endif
}

__device__ __forceinline__ uint32_t pack_h2(float a, float b) {
    U32H2 u; u.hh = __floats2half2_rn(a, b); return u.u;
}

__device__ __forceinline__ float sigmoidf_(float x) {
    return 1.0f / (1.0f + __expf(-x));
}
__device__ __forceinline__ float tanhf_(float x) {
    return 1.0f - 2.0f / (__expf(2.0f * x) + 1.0f);
}

// ---------- ws layout (bytes) ----------
#define OFF_WTAIL 393216
#define OFF_BIAS  524288
#define OFF_CONVF 528384
#define OFF_KSIM  529408
#define OFF_HOUT  530432

// ---------- prep: fp16 conversion + bias fuse ----------
__global__ void prep_kernel(const float* __restrict__ Whh,
                            const float* __restrict__ bih,
                            const float* __restrict__ bhh,
                            uint32_t* __restrict__ wreg,
                            uint32_t* __restrict__ wtail,
                            float* __restrict__ bias) {
    int gid = blockIdx.x * blockDim.x + threadIdx.x;  // 0..131071
    int row = gid >> 7;      // 0..1023
    int pr  = gid & 127;     // pair index, cols 2pr, 2pr+1
    float a = Whh[row * HID + 2 * pr];
    float b = Whh[row * HID + 2 * pr + 1];
    uint32_t p = pack_h2(a, b);
    if (pr < 96) {
        wreg[pr * G4 + row] = p;
    } else {
        int q = pr - 96;            // 0..31
        int c = q >> 2, d = q & 3;  // uint4 chunk 0..7, dword 0..3
        wtail[(c * G4 + row) * 4 + d] = p;
    }
    if (gid < G4) bias[gid] = bih[gid] + bhh[gid];
}

// ---------- features: conv mean + RBF kernel sim ----------
__global__ void feat_kernel(const float* __restrict__ x,
                            const float* __restrict__ conv_w,
                            const float* __restrict__ conv_b,
                            float* __restrict__ convf,
                            float* __restrict__ ksim) {
    int b = blockIdx.x, t = threadIdx.x;  // 256 threads
    const float4* xb = (const float4*)(x + (size_t)b * SEQ * IN_DIM);
    float cw0 = conv_w[0], cw1 = conv_w[1], cw2 = conv_w[2], cw3 = conv_w[3];
    float cb = conv_b[0];
    float s_sig = 0.f, s_sq = 0.f;
#pragma unroll
    for (int k = 0; k < 8; ++k) {
        int s = t + k * 256;
        float4 v = xb[s];
        float d = v.x * cw0 + v.y * cw1 + v.z * cw2 + v.w * cw3 + cb;
        s_sig += sigmoidf_(d);
        s_sq  += v.x * v.x + v.y * v.y + v.z * v.z + v.w * v.w;
    }
    __shared__ float sA[256], sB[256];
    sA[t] = s_sig; sB[t] = s_sq;
    __syncthreads();
    for (int off = 128; off > 0; off >>= 1) {
        if (t < off) { sA[t] += sA[t + off]; sB[t] += sB[t + off]; }
        __syncthreads();
    }
    if (t == 0) {
        convf[b] = sA[0] * (1.0f / 2048.0f);
        ksim[b]  = __expf(-sB[0]);
    }
}

// ---------- LSTM recurrence: 1 sample per block ----------
// 512 threads: thread t owns gate rows r1=t and r2=t+512.
//  t<256  : rows = (i_u, g_u), u=t      -> computes p=sigmoid(i)*tanh(g)
//  t>=256 : rows = (f_u, o_u), u=t-256  -> owns c_u, computes h_u
// LDS: wtail [8][1024] uint4 (128KB) + h double-buffer fp16 (2x512B) + p[256] f32
//
// __launch_bounds__(512, 2): 2nd arg = MIN WAVES PER EU. LDS (133KB) caps us
// at 1 block/CU = 8 waves = 2/EU regardless; declaring it raises the register
// allocator's budget to 256 VGPR/wave so w1[96]/w2[96] stay truly resident.
// (R1: no bound -> VGPR=120; R2: waves_per_eu attr ignored -> VGPR=124, both
// just under the 128 boundary for 4 waves/EU -> weights spilled every step.)
#define TAIL_DW (8 * 1024 * 4)

__global__ __launch_bounds__(512, 2)
void recur_kernel(const float* __restrict__ x,
                  const float* __restrict__ Wih,
                  const uint32_t* __restrict__ wreg,
                  const uint32_t* __restrict__ wtail,
                  const float* __restrict__ bias,
                  float* __restrict__ h_out) {
    extern __shared__ uint32_t smem[];
    uint32_t* tail  = smem;                 // TAIL_DW dwords (8192 uint4)
    uint32_t* hbuf0 = smem + TAIL_DW;       // 128 dwords (256 fp16)
    uint32_t* hbuf1 = hbuf0 + 128;          // 128 dwords
    float*    pbuf  = (float*)(hbuf1 + 128);// 256 floats

    const int b = blockIdx.x;
    const int t = threadIdx.x;
    const int r1 = t, r2 = t + 512;

    // stage w-tail into LDS (coalesced, layout identical)
    {
        const uint4* src = (const uint4*)wtail;
        uint4* dst = (uint4*)tail;
#pragma unroll
        for (int i = 0; i < 16; ++i) dst[t + i * 512] = src[t + i * 512];
    }
    if (t < 128) hbuf0[t] = 0u;  // h = 0 (fp16 zeros)

    // register-resident weights: pair-cols 0..95 of rows r1, r2
    uint32_t w1[96], w2[96];
#pragma unroll
    for (int k = 0; k < 96; ++k) {
        w1[k] = wreg[k * G4 + r1];
        w2[k] = wreg[k * G4 + r2];
    }
    // opaque no-op: pin values in VGPRs, forbid rematerialized reloads
#pragma unroll
    for (int k = 0; k < 96; ++k) {
        asm volatile("" : "+v"(w1[k]), "+v"(w2[k]));
    }

    const float4 wih1 = ((const float4*)Wih)[r1];
    const float4 wih2 = ((const float4*)Wih)[r2];
    const float bias1 = bias[r1], bias2 = bias[r2];

    float c_state = 0.f;
    float h_last = 0.f;
    const float4* xb = (const float4*)(x + (size_t)b * SEQ * IN_DIM);

    const uint4* tail4_1 = (const uint4*)tail + r1;   // + c*G4 per chunk
    const uint4* tail4_2 = (const uint4*)tail + r2;

    __syncthreads();

    uint32_t* hr = hbuf0;
    uint32_t* hw = hbuf1;

    for (int s = 0; s < SEQ; ++s) {
        const float4 xt = xb[s];
        float a1  = bias1 + xt.x * wih1.x + xt.y * wih1.y + xt.z * wih1.z + xt.w * wih1.w;
        float a2  = bias2 + xt.x * wih2.x + xt.y * wih2.y + xt.z * wih2.z + xt.w * wih2.w;
        float a1b = 0.f, a2b = 0.f;

        const uint4* hr4 = (const uint4*)hr;

        // main part: pair-cols 0..95 from registers, h broadcast from LDS
#pragma unroll
        for (int c = 0; c < 24; ++c) {
            const uint4 h4 = hr4[c];
            a1  = fdot2(w1[4 * c + 0], h4.x, a1);
            a2  = fdot2(w2[4 * c + 0], h4.x, a2);
            a1b = fdot2(w1[4 * c + 1], h4.y, a1b);
            a2b = fdot2(w2[4 * c + 1], h4.y, a2b);
            a1  = fdot2(w1[4 * c + 2], h4.z, a1);
            a2  = fdot2(w2[4 * c + 2], h4.z, a2);
            a1b = fdot2(w1[4 * c + 3], h4.w, a1b);
            a2b = fdot2(w2[4 * c + 3], h4.w, a2b);
        }
        // tail: pair-cols 96..127 from LDS (b128 reads)
#pragma unroll
        for (int c = 0; c < 8; ++c) {
            const uint4 wt1 = tail4_1[c * G4];
            const uint4 wt2 = tail4_2[c * G4];
            const uint4 h4  = hr4[24 + c];
            a1  = fdot2(wt1.x, h4.x, a1);
            a2  = fdot2(wt2.x, h4.x, a2);
            a1b = fdot2(wt1.y, h4.y, a1b);
            a2b = fdot2(wt2.y, h4.y, a2b);
            a1  = fdot2(wt1.z, h4.z, a1);
            a2  = fdot2(wt2.z, h4.z, a2);
            a1b = fdot2(wt1.w, h4.w, a1b);
            a2b = fdot2(wt2.w, h4.w, a2b);
        }
        const float z1 = a1 + a1b;
        const float z2 = a2 + a2b;

        if (t < 256) {
            // i, g -> p = sigmoid(i)*tanh(g)
            pbuf[t] = sigmoidf_(z1) * tanhf_(z2);
        }
        const float fg = sigmoidf_(z1);  // f (valid for t>=256)
        const float og = sigmoidf_(z2);  // o
        __syncthreads();
        if (t >= 256) {
            const int u = t - 256;
            c_state = fg * c_state + pbuf[u];
            h_last = og * tanhf_(c_state);
            ((__half*)hw)[u] = __float2half_rn(h_last);
        }
        __syncthreads();
        uint32_t* tmp = hr; hr = hw; hw = tmp;
    }

    if (t >= 256) h_out[b * HID + (t - 256)] = h_last;
}

// ---------- head: fc + relu + out + softmax ----------
__global__ void head_kernel(const float* __restrict__ fc_w,
                            const float* __restrict__ fc_b,
                            const float* __restrict__ out_w,
                            const float* __restrict__ out_b,
                            const float* __restrict__ convf,
                            const float* __restrict__ ksim,
                            const float* __restrict__ h_out,
                            float* __restrict__ out) {
    int b = blockIdx.x, j = threadIdx.x;  // 256 threads
    const float* hrow = h_out + b * HID;
    const float* w = fc_w + j * (HID + 2);
    float acc = fc_b[j] + w[0] * convf[b] + w[HID + 1] * ksim[b];
#pragma unroll 8
    for (int k = 0; k < HID; ++k) acc += w[1 + k] * hrow[k];
    float hid = fmaxf(acc, 0.f);
    __shared__ float r0[256], r1[256];
    r0[j] = hid * out_w[j];
    r1[j] = hid * out_w[HID + j];
    __syncthreads();
    for (int off = 128; off > 0; off >>= 1) {
        if (j < off) { r0[j] += r0[j + off]; r1[j] += r1[j + off]; }
        __syncthreads();
    }
    if (j == 0) {
        float l0 = r0[0] + out_b[0];
        float l1 = r1[0] + out_b[1];
        float m = fmaxf(l0, l1);
        float e0 = __expf(l0 - m), e1 = __expf(l1 - m);
        float inv = 1.0f / (e0 + e1);
        out[b * 2 + 0] = e0 * inv;
        out[b * 2 + 1] = e1 * inv;
    }
}

// ---------- launch ----------
extern "C" void kernel_launch(void* const* d_in, const int* in_sizes, int n_in,
                              void* d_out, int out_size, void* d_ws, size_t ws_size,
                              hipStream_t stream) {
    const float* x      = (const float*)d_in[0];
    const float* conv_w = (const float*)d_in[1];
    const float* conv_b = (const float*)d_in[2];
    const float* Wih    = (const float*)d_in[3];
    const float* Whh    = (const float*)d_in[4];
    const float* bih    = (const float*)d_in[5];
    const float* bhh    = (const float*)d_in[6];
    const float* fcw    = (const float*)d_in[7];
    const float* fcb    = (const float*)d_in[8];
    const float* outw   = (const float*)d_in[9];
    const float* outb   = (const float*)d_in[10];
    float* out = (float*)d_out;

    uint8_t* ws = (uint8_t*)d_ws;
    uint32_t* wreg  = (uint32_t*)ws;
    uint32_t* wtail = (uint32_t*)(ws + OFF_WTAIL);
    float* bias  = (float*)(ws + OFF_BIAS);
    float* convf = (float*)(ws + OFF_CONVF);
    float* ksim  = (float*)(ws + OFF_KSIM);
    float* h_out = (float*)(ws + OFF_HOUT);

    prep_kernel<<<512, 256, 0, stream>>>(Whh, bih, bhh, wreg, wtail, bias);
    feat_kernel<<<BATCH, 256, 0, stream>>>(x, conv_w, conv_b, convf, ksim);

    const size_t smem_bytes = (size_t)(TAIL_DW + 128 + 128 + 256) * 4;  // 133120 B
    hipFuncSetAttribute((const void*)recur_kernel,
                        hipFuncAttributeMaxDynamicSharedMemorySize, (int)smem_bytes);
    recur_kernel<<<BATCH, 512, smem_bytes, stream>>>(x, Wih, wreg, wtail, bias, h_out);

    head_kernel<<<BATCH, 256, 0, stream>>>(fcw, fcb, outw, outb, convf, ksim, h_out, out);
}